// Round 9
// baseline (182.534 us; speedup 1.0000x reference)
//
#include <hip/hip_runtime.h>
#include <math.h>

#define CHANNEL 128
#define NEG_INF (-1e30f)
#define MSTRIDE 52   // M is [128][52] col-padded: M[c*52+r] = P2[r][c]

__device__ __forceinline__ float dot4(float4 a, float4 b) {
    return a.x * b.x + a.y * b.y + a.z * b.z + a.w * b.w;
}

// blocks [0,R): prep  M[c][r] = ((W W^T relw[r]^T)/16)[c],  rel_norm[r] = ||relw[r]||^2
// blocks [R,..): count degrees + per-edge rank (atomic return order)
__global__ void __launch_bounds__(256) prep_count_kernel(
    const float* __restrict__ relw, const float* __restrict__ W,
    const int* __restrict__ eidx, float* __restrict__ M,
    float* __restrict__ rel_norm, int* __restrict__ deg,
    unsigned short* __restrict__ rank, int E, int R)
{
    int b = blockIdx.x;
    if (b < R) {
        __shared__ float rw[CHANNEL];
        __shared__ float kr[CHANNEL];
        __shared__ float red[CHANNEL];
        int c = threadIdx.x;
        int j = b;
        if (c < CHANNEL) {
            float v = relw[j * CHANNEL + c];
            rw[c] = v;
            red[c] = v * v;
        }
        __syncthreads();
        for (int s = CHANNEL / 2; s > 0; s >>= 1) {
            if (c < s) red[c] += red[c + s];
            __syncthreads();
        }
        if (c == 0) rel_norm[j] = red[0];
        if (c < CHANNEL) {
            float acc = 0.f;
            for (int k = 0; k < CHANNEL; ++k) acc += rw[k] * W[k * CHANNEL + c];
            kr[c] = acc;
        }
        __syncthreads();
        if (c < CHANNEL) {
            float acc2 = 0.f;
            for (int cc = 0; cc < CHANNEL; ++cc) acc2 += W[c * CHANNEL + cc] * kr[cc];
            M[c * MSTRIDE + j] = acc2 * 0.0625f;   // transposed store
        }
    } else {
        int e = (b - R) * 256 + threadIdx.x;
        if (e < E) rank[e] = (unsigned short)atomicAdd(deg + eidx[e], 1);
    }
}

// S[h][r] = dot(ent[h], M[:,r]); one wave per head, lane = relation slot
__global__ void __launch_bounds__(256) s_kernel(
    const float* __restrict__ ent, const float* __restrict__ M,
    float* __restrict__ S, int N, int R)
{
    int g = blockIdx.x * 256 + threadIdx.x;
    int h = g >> 6;
    int r = g & 63;
    if (h >= N) return;
    const float4* hp = (const float4*)(ent + (size_t)h * CHANNEL);
    float acc = 0.f;
    for (int c4 = 0; c4 < 32; ++c4) {
        float4 hv = hp[c4];                 // same addr across wave: broadcast
        int c = c4 * 4;
        acc += hv.x * M[(c    ) * MSTRIDE + r]
             + hv.y * M[(c + 1) * MSTRIDE + r]
             + hv.z * M[(c + 2) * MSTRIDE + r]
             + hv.w * M[(c + 3) * MSTRIDE + r];
    }
    if (r < R) S[(size_t)h * 50 + r] = acc;
}

// per-block (256) exclusive scan of deg; raw = local exclusive, partial = block totals
__global__ void scan1_kernel(const int* __restrict__ deg, int* __restrict__ raw,
                             int* __restrict__ partial, int N) {
    __shared__ int sh[256];
    int t = threadIdx.x;
    int i = blockIdx.x * 256 + t;
    int v = (i < N) ? deg[i] : 0;
    sh[t] = v;
    __syncthreads();
    for (int off = 1; off < 256; off <<= 1) {
        int u = (t >= off) ? sh[t - off] : 0;
        __syncthreads();
        sh[t] += u;
        __syncthreads();
    }
    if (i < N) raw[i] = sh[t] - v;
    if (t == 255) partial[blockIdx.x] = sh[255];
}

// single block: exclusive scan of block totals (nblk <= 1024)
__global__ void scan2_kernel(int* __restrict__ partial, int nblk) {
    __shared__ int sh[1024];
    int t = threadIdx.x;
    int v = (t < nblk) ? partial[t] : 0;
    sh[t] = v;
    __syncthreads();
    for (int off = 1; off < 1024; off <<= 1) {
        int u = (t >= off) ? sh[t - off] : 0;
        __syncthreads();
        sh[t] += u;
        __syncthreads();
    }
    if (t < nblk) partial[t] = sh[t] - v;
}

// atomic-free placement: recs[start(h) + rank[e]] = { tail | type<<20, edge_id }
__global__ void place_kernel(const int* __restrict__ eidx, const int* __restrict__ etype,
                             const int* __restrict__ raw, const int* __restrict__ partial,
                             const unsigned short* __restrict__ rank,
                             int2* __restrict__ recs, int E) {
    int e = blockIdx.x * 256 + threadIdx.x;
    if (e >= E) return;
    int h = eidx[e];
    int t = eidx[E + e];
    int r = etype[e] - 1;
    int pos = raw[h] + partial[h >> 8] + (int)rank[e];
    recs[pos] = make_int2(t | (r << 20), e);
}

struct Row { float4 t0, t1; };

// one wave per head; 16 lanes/edge; only tail rows gathered (d2 = S lookup);
// depth-3 pipelined, guarded issues
__global__ void __launch_bounds__(256, 6) main_kernel(
        const float* __restrict__ ent, const float* __restrict__ S,
        const float* __restrict__ rel_norm, const int* __restrict__ raw,
        const int* __restrict__ partial, const int2* __restrict__ recs,
        float* __restrict__ out, int N, int E) {
    int wid = (int)((blockIdx.x * blockDim.x + threadIdx.x) >> 6);
    if (wid >= N) return;
    int lane = threadIdx.x & 63;

    int s0 = raw[wid] + partial[wid >> 8];
    int nxt = (wid + 1 < N) ? (raw[wid + 1] + partial[(wid + 1) >> 8]) : E;
    int deg_h = nxt - s0;
    if (deg_h == 0) return;

    const float4* hp = (const float4*)(ent + (size_t)wid * CHANNEL);
    const float* Sh = S + (size_t)wid * 50;

    if (deg_h <= 64) {
        int grp = lane >> 4;   // edge slot 0..3
        int sub = lane & 15;   // row sixteenth
        float4 h0 = hp[sub], h1 = hp[sub + 16];

        // lane l owns edge l (clamped): coalesced 8B rec load
        int lc = lane < deg_h ? lane : deg_h - 1;
        int2 rc = recs[s0 + lc];
        int iters = (deg_h + 3) >> 2;

        auto issue = [&](int g) -> Row {
            Row s;
            if (g < iters) {   // uniform branch: no issues past the end
                int e = 4 * g + grp;
                int ec = e < deg_h ? e : deg_h - 1;
                int rcx = __shfl(rc.x, ec);
                int tail = rcx & 0xFFFFF;
                const float4* tp = (const float4*)(ent + (size_t)tail * CHANNEL);
                s.t0 = tp[sub]; s.t1 = tp[sub + 16];
            } else {
                s.t0 = s.t1 = make_float4(0.f, 0.f, 0.f, 0.f);
            }
            return s;
        };

        float d1c = 0.f;
        auto compute = [&](int g, const Row& s) {
            float d1 = dot4(h0, s.t0) + dot4(h1, s.t1);
#pragma unroll
            for (int m = 1; m <= 8; m <<= 1) d1 += __shfl_xor(d1, m);
            int srcl = (lane & 3) * 16;
            float td1 = __shfl(d1, srcl);
            if ((lane >> 2) == g) d1c = td1;
        };

        Row A = issue(0);
        Row B = issue(1);
        int g = 0;
        for (;;) {
            Row C = issue(g + 2);
            compute(g, A);
            if (++g >= iters) break;
            A = issue(g + 2);
            compute(g, B);
            if (++g >= iters) break;
            B = issue(g + 2);
            compute(g, C);
            if (++g >= iters) break;
        }

        bool valid = lane < deg_h;
        int typc = rc.x >> 20;
        int eidc = rc.y;
        float d2c = Sh[typc];                       // scalar lookup replaces dot
        // softmax 1 over d2
        float m1 = valid ? d2c : NEG_INF;
#pragma unroll
        for (int m = 32; m; m >>= 1) m1 = fmaxf(m1, __shfl_xor(m1, m));
        float e1 = valid ? expf(d2c - m1) : 0.f;
        float s1 = e1;
#pragma unroll
        for (int m = 32; m; m >>= 1) s1 += __shfl_xor(s1, m);
        float rs = e1 / s1;
        // trip score + softmax 2
        float stv = d1c + rs * rs * rel_norm[typc];
        float m2 = valid ? stv : NEG_INF;
#pragma unroll
        for (int m = 32; m; m >>= 1) m2 = fmaxf(m2, __shfl_xor(m2, m));
        float e2 = valid ? expf(stv - m2) : 0.f;
        float s2 = e2;
#pragma unroll
        for (int m = 32; m; m >>= 1) s2 += __shfl_xor(s2, m);
        if (valid) out[eidc] = e2 / s2;
    } else {
        // slow path (deg > 64; ~never): multi-sweep, out[] as scratch
        int grp = lane >> 4;
        int sub = lane & 15;
        float4 H0 = hp[sub], H1 = hp[sub + 16];

        // sweep 1: d1 -> out[eid]
        for (int k0 = 0; k0 < deg_h; k0 += 4) {
            int idx = k0 + grp;
            bool act = idx < deg_h;
            int j = s0 + (act ? idx : 0);
            int2 rc = recs[j];
            int tail = rc.x & 0xFFFFF;
            const float4* tp = (const float4*)(ent + (size_t)tail * CHANNEL);
            float d1 = dot4(H0, tp[sub]) + dot4(H1, tp[sub + 16]);
#pragma unroll
            for (int m = 1; m <= 8; m <<= 1) d1 += __shfl_xor(d1, m);
            if (act && sub == 0) out[rc.y] = d1;
        }
        // sweep 2: m1 over d2 = S[typ]
        float pm1 = NEG_INF;
        for (int k = lane; k < deg_h; k += 64)
            pm1 = fmaxf(pm1, Sh[recs[s0 + k].x >> 20]);
#pragma unroll
        for (int m = 32; m; m >>= 1) pm1 = fmaxf(pm1, __shfl_xor(pm1, m));
        float m1 = pm1;
        // sweep 3: s1
        float s1p = 0.f;
        for (int k = lane; k < deg_h; k += 64)
            s1p += expf(Sh[recs[s0 + k].x >> 20] - m1);
#pragma unroll
        for (int m = 32; m; m >>= 1) s1p += __shfl_xor(s1p, m);
        float s1 = s1p;
        // sweep 4: stv -> out[eid]; m2
        float pm2 = NEG_INF;
        for (int k = lane; k < deg_h; k += 64) {
            int2 rc = recs[s0 + k];
            int typ = rc.x >> 20;
            float e1 = expf(Sh[typ] - m1);
            float rsv = e1 / s1;
            float stv = out[rc.y] + rsv * rsv * rel_norm[typ];
            out[rc.y] = stv;
            pm2 = fmaxf(pm2, stv);
        }
#pragma unroll
        for (int m = 32; m; m >>= 1) pm2 = fmaxf(pm2, __shfl_xor(pm2, m));
        float m2 = pm2;
        // sweep 5: s2
        float s2p = 0.f;
        for (int k = lane; k < deg_h; k += 64)
            s2p += expf(out[recs[s0 + k].y] - m2);
#pragma unroll
        for (int m = 32; m; m >>= 1) s2p += __shfl_xor(s2p, m);
        float s2 = s2p;
        // sweep 6: normalize
        for (int k = lane; k < deg_h; k += 64) {
            int eid = recs[s0 + k].y;
            out[eid] = expf(out[eid] - m2) / s2;
        }
    }
}

extern "C" void kernel_launch(void* const* d_in, const int* in_sizes, int n_in,
                              void* d_out, int out_size, void* d_ws, size_t ws_size,
                              hipStream_t stream) {
    const float* ent   = (const float*)d_in[0];
    const float* relw  = (const float*)d_in[2];
    const float* W     = (const float*)d_in[3];
    const int*   eidx  = (const int*)d_in[4];
    const int*   etype = (const int*)d_in[5];
    float* out = (float*)d_out;

    const int E = in_sizes[5];
    const int N = in_sizes[0] / CHANNEL;
    const int R = in_sizes[2] / CHANNEL;

    char* base = (char*)d_ws;
    auto alloc = [&](size_t bytes) {
        char* p = base;
        base += (bytes + 15) & ~(size_t)15;
        return p;
    };
    int*    deg      = (int*)alloc((size_t)N * 4);
    int*    raw      = (int*)alloc((size_t)N * 4);
    int*    partial  = (int*)alloc(1024 * 4);
    int2*   recs     = (int2*)alloc((size_t)E * 8);
    float*  M        = (float*)alloc((size_t)CHANNEL * MSTRIDE * 4);
    float*  rel_norm = (float*)alloc((size_t)R * 4);
    float*  S        = (float*)alloc((size_t)N * 50 * 4);
    unsigned short* rank = (unsigned short*)alloc((size_t)E * 2);

    hipMemsetAsync(deg, 0, (size_t)N * 4, stream);

    int ceblk = (E + 255) / 256;
    prep_count_kernel<<<R + ceblk, 256, 0, stream>>>(relw, W, eidx, M, rel_norm,
                                                     deg, rank, E, R);

    s_kernel<<<(N * 64 + 255) / 256, 256, 0, stream>>>(ent, M, S, N, R);

    int nblk = (N + 255) / 256;  // 157 for N=40000; must be <= 1024
    scan1_kernel<<<nblk, 256, 0, stream>>>(deg, raw, partial, N);
    scan2_kernel<<<1, 1024, 0, stream>>>(partial, nblk);

    place_kernel<<<ceblk, 256, 0, stream>>>(eidx, etype, raw, partial, rank, recs, E);

    int bm = (N + 3) / 4;  // 4 waves per block, one wave per head
    main_kernel<<<bm, 256, 0, stream>>>(ent, S, rel_norm, raw, partial, recs, out, N, E);
}